// Round 2
// baseline (345.680 us; speedup 1.0000x reference)
//
#include <hip/hip_runtime.h>

#define TOTAL  4194304
#define DIM    32
#define NTOK   (TOTAL / DIM)   // 131072 tokens
#define NCODE  1024

// Precompute hb[k] = 0.5 * |e_k|^2 into workspace (one block, one thread per code).
__global__ __launch_bounds__(1024) void vq_prep_kernel(
    const float* __restrict__ cb, float* __restrict__ hb)
{
    const int k = threadIdx.x;   // 1024 codes
    const float4* e4 = reinterpret_cast<const float4*>(cb) + (size_t)k * 8;
    float e2 = 0.0f;
#pragma unroll
    for (int j = 0; j < 8; ++j) {
        float4 v = e4[j];
        e2 = fmaf(v.x, v.x, e2);
        e2 = fmaf(v.y, v.y, e2);
        e2 = fmaf(v.z, v.z, e2);
        e2 = fmaf(v.w, v.w, e2);
    }
    hb[k] = 0.5f * e2;
}

// argmin_k |x - e_k|^2  ==  argmax_k ( x . e_k - |e_k|^2 / 2 )
// Codebook accesses are wave-uniform -> compiler emits s_load into SGPRs,
// scalar pipe overlaps the VALU fma chain. No LDS at all.
__global__ __launch_bounds__(256) void vq_argmax_kernel(
    const float* __restrict__ w,
    const float* __restrict__ c,
    const float* __restrict__ cb,
    const float* __restrict__ hb,
    int* __restrict__ out)
{
    const int t = blockIdx.x * 256 + threadIdx.x;   // token id

    // x = w - c, 32 consecutive floats per token, kept in VGPRs
    float x[DIM];
    const float4* w4 = reinterpret_cast<const float4*>(w) + (size_t)t * 8;
    const float4* c4 = reinterpret_cast<const float4*>(c) + (size_t)t * 8;
#pragma unroll
    for (int j = 0; j < 8; ++j) {
        float4 a = w4[j];
        float4 b = c4[j];
        x[4 * j + 0] = a.x - b.x;
        x[4 * j + 1] = a.y - b.y;
        x[4 * j + 2] = a.z - b.z;
        x[4 * j + 3] = a.w - b.w;
    }

    float smax = -INFINITY;
    int   best = 0;

    for (int k = 0; k < NCODE; ++k) {
        const float* e = cb + (size_t)k * DIM;   // wave-uniform -> SGPRs
        float acc = -hb[k];                      // wave-uniform -> SGPR
#pragma unroll
        for (int i = 0; i < DIM; ++i) acc = fmaf(x[i], e[i], acc);
        if (acc > smax) { smax = acc; best = k; }   // strict > => first-max == first-min of d
    }

    out[t] = best;
}

extern "C" void kernel_launch(void* const* d_in, const int* in_sizes, int n_in,
                              void* d_out, int out_size, void* d_ws, size_t ws_size,
                              hipStream_t stream) {
    const float* w  = (const float*)d_in[0];   // weights  [4194304]
    const float* c  = (const float*)d_in[1];   // condition [1,32,131072] flat
    const float* cb = (const float*)d_in[2];   // codebook [1024,32]
    int*   out = (int*)d_out;                  // int32 indices [131072]
    float* hb  = (float*)d_ws;                 // 1024 floats of scratch

    vq_prep_kernel<<<1, NCODE, 0, stream>>>(cb, hb);
    vq_argmax_kernel<<<NTOK / 256, 256, 0, stream>>>(w, c, cb, hb, out);
}

// Round 3
// 155.517 us; speedup vs baseline: 2.2228x; 2.2228x over previous
//
#include <hip/hip_runtime.h>

#define TOTAL   4194304
#define DIM     32
#define NTOK    (TOTAL / DIM)   // 131072 tokens
#define NCODE   1024
#define DELTA   0.02f
#define FLAGBIT 0x40000000

typedef _Float16 half8   __attribute__((ext_vector_type(8)));
typedef float    floatx4 __attribute__((ext_vector_type(4)));

// ---------------- prep: codebook -> f16 hi/lo split + (-0.5*|e|^2) ----------------
__global__ __launch_bounds__(256) void vq_prep(
    const float* __restrict__ cb, float* __restrict__ nhb,
    _Float16* __restrict__ Eh, _Float16* __restrict__ El)
{
    const int k = blockIdx.x * 256 + threadIdx.x;   // code id (4 blocks x 256)
    const float* e = cb + k * DIM;
    float e2 = 0.0f;
#pragma unroll
    for (int i = 0; i < DIM; ++i) {
        float v = e[i];
        e2 = fmaf(v, v, e2);
        _Float16 h = (_Float16)v;
        Eh[k * DIM + i] = h;
        El[k * DIM + i] = (_Float16)(v - (float)h);
    }
    nhb[k] = -0.5f * e2;
}

// ---------------- main: MFMA argmax of (x.e - |e|^2/2), margin-flagged ----------------
// argmin_k |x-e_k|^2 == argmax_k (x.e_k - |e_k|^2/2)
// x.e via split-f16: xh*eh + xh*el + xl*eh  (error ~1e-4 << DELTA)
__global__ __launch_bounds__(256) void vq_main(
    const float* __restrict__ w, const float* __restrict__ c,
    const float* __restrict__ nhb, const _Float16* __restrict__ Eh,
    const _Float16* __restrict__ El, int* __restrict__ out)
{
    __shared__ _Float16 sEh[256 * DIM];   // 16 KB
    __shared__ _Float16 sEl[256 * DIM];   // 16 KB
    __shared__ float    snhb[256];        // 1 KB

    const int tid  = threadIdx.x;
    const int lane = tid & 63;
    const int wid  = tid >> 6;                     // wave 0..3
    const int tok0 = blockIdx.x * 256 + wid * 64;  // 64 tokens per wave
    const int l15  = lane & 15;
    const int l4   = lane >> 4;                    // 0..3

    // A fragments: 4 tiles of 16 tokens. A[row=l15][k=l4*8+j]
    half8 xh[4], xl[4];
#pragma unroll
    for (int m = 0; m < 4; ++m) {
        const int token = tok0 + m * 16 + l15;
        const float4* pw = reinterpret_cast<const float4*>(w + token * DIM + l4 * 8);
        const float4* pc = reinterpret_cast<const float4*>(c + token * DIM + l4 * 8);
        float4 a0 = pw[0], a1 = pw[1], b0 = pc[0], b1 = pc[1];
        float xs[8] = {a0.x - b0.x, a0.y - b0.y, a0.z - b0.z, a0.w - b0.w,
                       a1.x - b1.x, a1.y - b1.y, a1.z - b1.z, a1.w - b1.w};
#pragma unroll
        for (int j = 0; j < 8; ++j) {
            _Float16 h = (_Float16)xs[j];
            xh[m][j] = h;
            xl[m][j] = (_Float16)(xs[j] - (float)h);
        }
    }

    float best[16], second[16];
    int   bidx[16];
#pragma unroll
    for (int q = 0; q < 16; ++q) { best[q] = -INFINITY; second[q] = -INFINITY; bidx[q] = 0; }

    for (int chunk = 0; chunk < 4; ++chunk) {
        __syncthreads();
        {   // stage 256 codes (hi, lo, nhb) into LDS; thread tid owns one code
            const int g = chunk * 256 + tid;
            const uint4* srcH = reinterpret_cast<const uint4*>(Eh + (size_t)g * DIM);
            const uint4* srcL = reinterpret_cast<const uint4*>(El + (size_t)g * DIM);
            uint4* dstH = reinterpret_cast<uint4*>(sEh + tid * DIM);
            uint4* dstL = reinterpret_cast<uint4*>(sEl + tid * DIM);
#pragma unroll
            for (int j = 0; j < 4; ++j) { dstH[j] = srcH[j]; dstL[j] = srcL[j]; }
            snhb[tid] = nhb[g];
        }
        __syncthreads();

        for (int step = 0; step < 16; ++step) {
            const int row = step * 16 + l15;        // code within chunk (B col = l15)
            const half8 eh = *reinterpret_cast<const half8*>(sEh + row * DIM + l4 * 8);
            const half8 el = *reinterpret_cast<const half8*>(sEl + row * DIM + l4 * 8);
            const float nh = snhb[row];
            const int   myk = chunk * 256 + step * 16 + l15;
#pragma unroll
            for (int m = 0; m < 4; ++m) {
                floatx4 acc1 = {nh, nh, nh, nh};
                floatx4 acc2 = {0.f, 0.f, 0.f, 0.f};
                acc1 = __builtin_amdgcn_mfma_f32_16x16x32_f16(xh[m], eh, acc1, 0, 0, 0);
                acc2 = __builtin_amdgcn_mfma_f32_16x16x32_f16(xh[m], el, acc2, 0, 0, 0);
                acc2 = __builtin_amdgcn_mfma_f32_16x16x32_f16(xl[m], eh, acc2, 0, 0, 0);
#pragma unroll
                for (int r = 0; r < 4; ++r) {
                    const int q = m * 4 + r;
                    float s = acc1[r] + acc2[r];
                    bool gt = s > best[q];
                    second[q] = fmaxf(second[q], fminf(s, best[q]));
                    best[q] = gt ? s : best[q];
                    bidx[q] = gt ? myk : bidx[q];
                }
            }
        }
    }

    // reduce across the 16 columns (lanes differing in bits 0..3)
#pragma unroll
    for (int sh = 1; sh < 16; sh <<= 1) {
#pragma unroll
        for (int q = 0; q < 16; ++q) {
            float bB = __shfl_xor(best[q], sh);
            float sB = __shfl_xor(second[q], sh);
            int   iB = __shfl_xor(bidx[q], sh);
            float cand = fminf(best[q], bB);
            second[q] = fmaxf(fmaxf(second[q], sB), cand);
            bool take = (bB > best[q]) || (bB == best[q] && iB < bidx[q]);
            best[q] = take ? bB : best[q];
            bidx[q] = take ? iB : bidx[q];
        }
    }

    // D rows: token = tok0 + m*16 + l4*4 + r; lanes with l15==0 write
    if (l15 == 0) {
#pragma unroll
        for (int m = 0; m < 4; ++m) {
#pragma unroll
            for (int r = 0; r < 4; ++r) {
                const int q = m * 4 + r;
                const int token = tok0 + m * 16 + l4 * 4 + r;
                int v = bidx[q];
                if (best[q] - second[q] < DELTA) v |= FLAGBIT;
                out[token] = v;
            }
        }
    }
}

// ---------------- rescore: exact fp32 (R1 formula) for flagged tokens ----------------
__global__ __launch_bounds__(256) void vq_rescore(
    const float* __restrict__ w, const float* __restrict__ c,
    const float* __restrict__ cb, int* __restrict__ out)
{
    const int tid  = threadIdx.x;
    const int lane = tid & 63;
    const int wid  = tid >> 6;
    const int t0   = blockIdx.x * 256 + wid * 64;

    int v = out[t0 + lane];
    unsigned long long mask = __ballot((v & FLAGBIT) != 0);
    while (mask) {
        const int src = __ffsll((unsigned long long)mask) - 1;
        mask &= mask - 1;
        const int token = t0 + src;   // wave-uniform

        float x[DIM];
#pragma unroll
        for (int i = 0; i < DIM; ++i) x[i] = w[token * DIM + i] - c[token * DIM + i];
        float x2 = 0.f;
#pragma unroll
        for (int i = 0; i < DIM; ++i) x2 = fmaf(x[i], x[i], x2);

        float dmin = INFINITY;
        int   kbest = 0;
        for (int i = 0; i < 16; ++i) {
            const int k = lane + 64 * i;           // ascending per lane
            const float* e = cb + k * DIM;
            float dot = 0.f, e2 = 0.f;
#pragma unroll
            for (int j = 0; j < DIM; ++j) {
                float ev = e[j];
                dot = fmaf(x[j], ev, dot);
                e2  = fmaf(ev, ev, e2);
            }
            float dd = fmaf(-2.0f, dot, x2) + e2;
            if (dd < dmin) { dmin = dd; kbest = k; }
        }
#pragma unroll
        for (int sh = 1; sh < 64; sh <<= 1) {
            float dB = __shfl_xor(dmin, sh);
            int   iB = __shfl_xor(kbest, sh);
            bool take = (dB < dmin) || (dB == dmin && iB < kbest);
            dmin = take ? dB : dmin;
            kbest = take ? iB : kbest;
        }
        if (lane == src) out[token] = kbest;   // clears flag bit
    }
}

extern "C" void kernel_launch(void* const* d_in, const int* in_sizes, int n_in,
                              void* d_out, int out_size, void* d_ws, size_t ws_size,
                              hipStream_t stream) {
    const float* w  = (const float*)d_in[0];   // weights   [4194304]
    const float* c  = (const float*)d_in[1];   // condition [1,32,131072] flat (elementwise vs w)
    const float* cb = (const float*)d_in[2];   // codebook  [1024,32]
    int* out = (int*)d_out;                    // int32 indices [131072]

    char* wsb = (char*)d_ws;
    float*    nhb = (float*)wsb;                       // 4 KB
    _Float16* Eh  = (_Float16*)(wsb + 4096);           // 64 KB
    _Float16* El  = (_Float16*)(wsb + 4096 + 65536);   // 64 KB

    vq_prep<<<NCODE / 256, 256, 0, stream>>>(cb, nhb, Eh, El);
    vq_main<<<NTOK / 256, 256, 0, stream>>>(w, c, nhb, Eh, El, out);
    vq_rescore<<<NTOK / 256, 256, 0, stream>>>(w, c, cb, out);
}

// Round 4
// 77.225 us; speedup vs baseline: 4.4762x; 2.0138x over previous
//
#include <hip/hip_runtime.h>

#define TOTAL     4194304
#define DIM       32
#define NTOK      (TOTAL / DIM)   // 131072 tokens
#define NCODE     1024
#define CHUNK     256
#define DELTA_EPS 2e-3f
#define FLAGBIT   0x40000000

typedef _Float16 half8   __attribute__((ext_vector_type(8)));
typedef float    floatx4 __attribute__((ext_vector_type(4)));

// ---------------- prep: codebook -> f16 hi/lo split + (-0.5*|e|^2) ----------------
__global__ __launch_bounds__(256) void vq_prep(
    const float* __restrict__ cb, float* __restrict__ nhb,
    _Float16* __restrict__ Eh, _Float16* __restrict__ El)
{
    const int k = blockIdx.x * 256 + threadIdx.x;
    const float* e = cb + k * DIM;
    float e2 = 0.0f;
#pragma unroll
    for (int i = 0; i < DIM; ++i) {
        float v = e[i];
        e2 = fmaf(v, v, e2);                      // sequential: matches rescore exactly
        _Float16 h = (_Float16)v;
        Eh[k * DIM + i] = h;
        El[k * DIM + i] = (_Float16)(v - (float)h);
    }
    nhb[k] = -0.5f * e2;
}

// ---------------- main: MFMA argmax of (x.e - |e|^2/2), packed-index scores ----------------
// score packed as: (fp32 bits & ~1023) | (1023 - k)  -> float max == (value, smallest-k) argmax
__global__ __launch_bounds__(256) void vq_main(
    const float* __restrict__ w, const float* __restrict__ c,
    const float* __restrict__ nhb, const _Float16* __restrict__ Eh,
    const _Float16* __restrict__ El, int* __restrict__ out)
{
    __shared__ _Float16 sEh[CHUNK * DIM];   // 16 KB
    __shared__ _Float16 sEl[CHUNK * DIM];   // 16 KB
    __shared__ float    snh[CHUNK];         // 1 KB

    const int tid  = threadIdx.x;
    const int lane = tid & 63;
    const int wid  = tid >> 6;
    const int tok0 = blockIdx.x * 128 + wid * 32;   // 32 tokens per wave
    const int l15  = lane & 15;
    const int l4   = lane >> 4;

    // A fragments: 2 tiles of 16 tokens. A[row=l15][k=l4*8+j]
    half8 xh[2], xl[2];
#pragma unroll
    for (int m = 0; m < 2; ++m) {
        const int token = tok0 + m * 16 + l15;
        const float4* pw = reinterpret_cast<const float4*>(w + (size_t)token * DIM + l4 * 8);
        const float4* pc = reinterpret_cast<const float4*>(c + (size_t)token * DIM + l4 * 8);
        float4 a0 = pw[0], a1 = pw[1], b0 = pc[0], b1 = pc[1];
        float xs[8] = {a0.x - b0.x, a0.y - b0.y, a0.z - b0.z, a0.w - b0.w,
                       a1.x - b1.x, a1.y - b1.y, a1.z - b1.z, a1.w - b1.w};
#pragma unroll
        for (int j = 0; j < 8; ++j) {
            _Float16 h = (_Float16)xs[j];
            xh[m][j] = h;
            xl[m][j] = (_Float16)(xs[j] - (float)h);
        }
    }

    const float NEGINF = __uint_as_float(0xFF800000u);
    float best[8], second[8];
#pragma unroll
    for (int q = 0; q < 8; ++q) { best[q] = NEGINF; second[q] = NEGINF; }

    for (int chunk = 0; chunk < 4; ++chunk) {
        __syncthreads();
        {   // stage 256 codes (hi, lo, nh); thread tid owns one code
            const int g = chunk * 256 + tid;
            const uint4* srcH = reinterpret_cast<const uint4*>(Eh + (size_t)g * DIM);
            const uint4* srcL = reinterpret_cast<const uint4*>(El + (size_t)g * DIM);
            uint4* dstH = reinterpret_cast<uint4*>(sEh + tid * DIM);
            uint4* dstL = reinterpret_cast<uint4*>(sEl + tid * DIM);
#pragma unroll
            for (int j = 0; j < 4; ++j) { dstH[j] = srcH[j]; dstL[j] = srcL[j]; }
            snh[tid] = nhb[g];
        }
        __syncthreads();

        // 16 steps of 16 codes, processed in pairs (for med3 second-tracking)
#pragma unroll
        for (int sp = 0; sp < 8; ++sp) {
            const int codeA = (2 * sp) * 16 + l15;
            const int codeB = (2 * sp + 1) * 16 + l15;
            const half8 ehA = *reinterpret_cast<const half8*>(sEh + codeA * DIM + l4 * 8);
            const half8 elA = *reinterpret_cast<const half8*>(sEl + codeA * DIM + l4 * 8);
            const half8 ehB = *reinterpret_cast<const half8*>(sEh + codeB * DIM + l4 * 8);
            const half8 elB = *reinterpret_cast<const half8*>(sEl + codeB * DIM + l4 * 8);
            const float nhA = snh[codeA];
            const float nhB = snh[codeB];
            const unsigned ixA = 1023u - (unsigned)(chunk * 256 + codeA);
            const unsigned ixB = 1023u - (unsigned)(chunk * 256 + codeB);
            const floatx4 nA = {nhA, nhA, nhA, nhA};
            const floatx4 nB = {nhB, nhB, nhB, nhB};
#pragma unroll
            for (int m = 0; m < 2; ++m) {
                floatx4 aA = nA, aB = nB;
                aA = __builtin_amdgcn_mfma_f32_16x16x32_f16(xh[m], ehA, aA, 0, 0, 0);
                aA = __builtin_amdgcn_mfma_f32_16x16x32_f16(xl[m], ehA, aA, 0, 0, 0);
                aA = __builtin_amdgcn_mfma_f32_16x16x32_f16(xh[m], elA, aA, 0, 0, 0);
                aB = __builtin_amdgcn_mfma_f32_16x16x32_f16(xh[m], ehB, aB, 0, 0, 0);
                aB = __builtin_amdgcn_mfma_f32_16x16x32_f16(xl[m], ehB, aB, 0, 0, 0);
                aB = __builtin_amdgcn_mfma_f32_16x16x32_f16(xh[m], elB, aB, 0, 0, 0);
#pragma unroll
                for (int r = 0; r < 4; ++r) {
                    const int q = m * 4 + r;
                    float pA = __uint_as_float((__float_as_uint(aA[r]) & 0xFFFFFC00u) | ixA);
                    float pB = __uint_as_float((__float_as_uint(aB[r]) & 0xFFFFFC00u) | ixB);
                    float t  = __builtin_amdgcn_fmed3f(pA, pB, best[q]);  // 2nd of {pA,pB,best}
                    second[q] = fmaxf(second[q], t);
                    best[q]   = fmaxf(fmaxf(best[q], pA), pB);            // -> v_max3
                }
            }
        }
    }

    // reduce across the 16 code-lanes (xor over lane bits 0..3)
#pragma unroll
    for (int sh = 1; sh < 16; sh <<= 1) {
#pragma unroll
        for (int q = 0; q < 8; ++q) {
            float bB = __shfl_xor(best[q], sh);
            float sB = __shfl_xor(second[q], sh);
            second[q] = fmaxf(fmaxf(second[q], sB), fminf(best[q], bB));
            best[q]   = fmaxf(best[q], bB);
        }
    }

    if (l15 == 0) {
#pragma unroll
        for (int m = 0; m < 2; ++m) {
#pragma unroll
            for (int r = 0; r < 4; ++r) {
                const int q = m * 4 + r;
                const int token = tok0 + m * 16 + l4 * 4 + r;
                unsigned ub = __float_as_uint(best[q]);
                unsigned us = __float_as_uint(second[q]);
                float bv = __uint_as_float(ub & 0xFFFFFC00u);
                float sv = __uint_as_float(us & 0xFFFFFC00u);
                int eb = (int)((ub >> 23) & 255u);
                int es = (int)((us >> 23) & 255u);
                int em = eb > es ? eb : es;
                em = em > 12 ? em : 12;
                // flag threshold = 4 * packing granule (2^(em-127-12)) + eps
                float thr = __uint_as_float((unsigned)(em - 11) << 23) + DELTA_EPS;
                int k = 1023 - (int)(ub & 1023u);
                out[token] = ((bv - sv) < thr) ? (k | FLAGBIT) : k;
            }
        }
    }
}

// ---------------- rescore: exact fp32 (R1 formula) for flagged tokens ----------------
__global__ __launch_bounds__(256) void vq_rescore(
    const float* __restrict__ w, const float* __restrict__ c,
    const float* __restrict__ cb, const float* __restrict__ nhb,
    int* __restrict__ out)
{
    const int tid  = threadIdx.x;
    const int lane = tid & 63;
    const int wid  = tid >> 6;
    const int t0   = blockIdx.x * 256 + wid * 64;

    int v = out[t0 + lane];
    unsigned long long mask = __ballot((v & FLAGBIT) != 0);
    while (mask) {
        const int src = __ffsll((unsigned long long)mask) - 1;
        mask &= mask - 1;
        const int token = t0 + src;   // wave-uniform

        float x[DIM];
#pragma unroll
        for (int i = 0; i < DIM; ++i) x[i] = w[token * DIM + i] - c[token * DIM + i];
        float x2 = 0.f;
#pragma unroll
        for (int i = 0; i < DIM; ++i) x2 = fmaf(x[i], x[i], x2);

        float dmin = INFINITY;
        int   kbest = 0;
#pragma unroll 2
        for (int i = 0; i < 16; ++i) {
            const int k = lane + 64 * i;           // ascending per lane
            const float* e = cb + k * DIM;
            float dot = 0.f;
#pragma unroll
            for (int j = 0; j < DIM; ++j) dot = fmaf(x[j], e[j], dot);
            float e2 = -2.0f * nhb[k];             // bit-exact |e|^2 (seq-fma in prep)
            float dd = fmaf(-2.0f, dot, x2) + e2;
            if (dd < dmin) { dmin = dd; kbest = k; }
        }
#pragma unroll
        for (int sh = 1; sh < 64; sh <<= 1) {
            float dB = __shfl_xor(dmin, sh);
            int   iB = __shfl_xor(kbest, sh);
            bool take = (dB < dmin) || (dB == dmin && iB < kbest);
            dmin = take ? dB : dmin;
            kbest = take ? iB : kbest;
        }
        if (lane == src) out[token] = kbest;   // clears flag bit
    }
}

extern "C" void kernel_launch(void* const* d_in, const int* in_sizes, int n_in,
                              void* d_out, int out_size, void* d_ws, size_t ws_size,
                              hipStream_t stream) {
    const float* w  = (const float*)d_in[0];   // weights   [4194304]
    const float* c  = (const float*)d_in[1];   // condition [1,32,131072] flat
    const float* cb = (const float*)d_in[2];   // codebook  [1024,32]
    int* out = (int*)d_out;                    // int32 indices [131072]

    char* wsb = (char*)d_ws;
    float*    nhb = (float*)wsb;                       // 4 KB
    _Float16* Eh  = (_Float16*)(wsb + 4096);           // 64 KB
    _Float16* El  = (_Float16*)(wsb + 4096 + 65536);   // 64 KB

    vq_prep<<<NCODE / 256, 256, 0, stream>>>(cb, nhb, Eh, El);
    vq_main<<<NTOK / 128, 256, 0, stream>>>(w, c, nhb, Eh, El, out);
    vq_rescore<<<NTOK / 256, 256, 0, stream>>>(w, c, cb, nhb, out);
}

// Round 5
// 73.374 us; speedup vs baseline: 4.7112x; 1.0525x over previous
//
#include <hip/hip_runtime.h>

#define TOTAL     4194304
#define DIM       32
#define NTOK      (TOTAL / DIM)   // 131072 tokens
#define NCODE     1024
#define DELTA_EPS 2e-3f
#define FLAGBIT   0x40000000

typedef _Float16 half8   __attribute__((ext_vector_type(8)));
typedef float    floatx4 __attribute__((ext_vector_type(4)));

#define GLOAD_LDS16(g, l) \
    __builtin_amdgcn_global_load_lds((const __attribute__((address_space(1))) void*)(g), \
                                     (__attribute__((address_space(3))) void*)(l), 16, 0, 0)
#define GLOAD_LDS4(g, l) \
    __builtin_amdgcn_global_load_lds((const __attribute__((address_space(1))) void*)(g), \
                                     (__attribute__((address_space(3))) void*)(l), 4, 0, 0)

// ---------------- prep: codebook -> f16 hi/lo split in FRAGMENT ORDER + (-0.5*|e|^2) ----
// Fragment slot for code k, k-quarter l4:  [chunk][step*64 + l4*16 + l15], 8 halves each.
// Main then reads/stages with purely linear (lane*16B) addresses -> zero bank conflicts.
__global__ __launch_bounds__(64) void vq_prep(
    const float* __restrict__ cb, float* __restrict__ nhb,
    _Float16* __restrict__ Eh, _Float16* __restrict__ El)
{
    const int k = blockIdx.x * 64 + threadIdx.x;   // code id
    const float4* e4 = reinterpret_cast<const float4*>(cb) + (size_t)k * 8;
    float v[DIM];
    float4 t[8];
#pragma unroll
    for (int j = 0; j < 8; ++j) t[j] = e4[j];
#pragma unroll
    for (int j = 0; j < 8; ++j) {
        v[4 * j + 0] = t[j].x; v[4 * j + 1] = t[j].y;
        v[4 * j + 2] = t[j].z; v[4 * j + 3] = t[j].w;
    }
    float e2 = 0.0f;
#pragma unroll
    for (int i = 0; i < DIM; ++i) e2 = fmaf(v[i], v[i], e2);   // sequential: matches rescore
    nhb[k] = -0.5f * e2;

    const int chunk = k >> 8, within = k & 255;
    const int step = within >> 4, l15 = within & 15;
#pragma unroll
    for (int l4 = 0; l4 < 4; ++l4) {
        half8 h, lo;
#pragma unroll
        for (int j = 0; j < 8; ++j) {
            float x = v[l4 * 8 + j];
            _Float16 hh = (_Float16)x;
            h[j]  = hh;
            lo[j] = (_Float16)(x - (float)hh);
        }
        const int slot = chunk * 1024 + step * 64 + l4 * 16 + l15;
        *reinterpret_cast<half8*>(Eh + (size_t)slot * 8) = h;
        *reinterpret_cast<half8*>(El + (size_t)slot * 8) = lo;
    }
}

// ---------------- main: MFMA argmax of (x.e - |e|^2/2), packed-index scores ----------------
__global__ __launch_bounds__(256) void vq_main(
    const float* __restrict__ w, const float* __restrict__ c,
    const float* __restrict__ nhb, const _Float16* __restrict__ Eh,
    const _Float16* __restrict__ El, int* __restrict__ out)
{
    __shared__ _Float16 sEh[1024 * 8];   // 16 KB: [step(16)][lane(64)][8 halves]
    __shared__ _Float16 sEl[1024 * 8];   // 16 KB
    __shared__ float    snh[256];        // 1 KB

    const int tid  = threadIdx.x;
    const int lane = tid & 63;
    const int wid  = tid >> 6;
    const int tok0 = blockIdx.x * 128 + wid * 32;   // 32 tokens per wave
    const int l15  = lane & 15;
    const int l4   = lane >> 4;

    // A fragments: 2 tiles of 16 tokens. A[row=l15][k=l4*8+j]
    half8 xh[2], xl[2];
#pragma unroll
    for (int m = 0; m < 2; ++m) {
        const int token = tok0 + m * 16 + l15;
        const float4* pw = reinterpret_cast<const float4*>(w + (size_t)token * DIM + l4 * 8);
        const float4* pc = reinterpret_cast<const float4*>(c + (size_t)token * DIM + l4 * 8);
        float4 a0 = pw[0], a1 = pw[1], b0 = pc[0], b1 = pc[1];
        float xs[8] = {a0.x - b0.x, a0.y - b0.y, a0.z - b0.z, a0.w - b0.w,
                       a1.x - b1.x, a1.y - b1.y, a1.z - b1.z, a1.w - b1.w};
#pragma unroll
        for (int j = 0; j < 8; ++j) {
            _Float16 h = (_Float16)xs[j];
            xh[m][j] = h;
            xl[m][j] = (_Float16)(xs[j] - (float)h);
        }
    }

    const float NEGINF = __uint_as_float(0xFF800000u);
    float best[8], second[8];
#pragma unroll
    for (int q = 0; q < 8; ++q) { best[q] = NEGINF; second[q] = NEGINF; }

    for (int chunk = 0; chunk < 4; ++chunk) {
        // ---- stage 256 codes via async global->LDS, all-linear addressing
        {
            const _Float16* gh = Eh + (size_t)chunk * 8192;
            const _Float16* gl = El + (size_t)chunk * 8192;
#pragma unroll
            for (int r2 = 0; r2 < 4; ++r2) {
                const int slot = r2 * 256 + wid * 64;   // wave-uniform LDS base slot
                GLOAD_LDS16(gh + (size_t)(slot + lane) * 8, sEh + (size_t)slot * 8);
                GLOAD_LDS16(gl + (size_t)(slot + lane) * 8, sEl + (size_t)slot * 8);
            }
            GLOAD_LDS4(nhb + chunk * 256 + wid * 64 + lane, snh + wid * 64);
        }
        __syncthreads();   // drains vmcnt before barrier -> data visible

        // 16 steps of 16 codes, processed in pairs (for med3 second-tracking)
#pragma unroll
        for (int sp = 0; sp < 8; ++sp) {
            const int sA = 2 * sp, sB = 2 * sp + 1;
            const half8 ehA = *reinterpret_cast<const half8*>(sEh + (sA * 64 + lane) * 8);
            const half8 elA = *reinterpret_cast<const half8*>(sEl + (sA * 64 + lane) * 8);
            const half8 ehB = *reinterpret_cast<const half8*>(sEh + (sB * 64 + lane) * 8);
            const half8 elB = *reinterpret_cast<const half8*>(sEl + (sB * 64 + lane) * 8);
            const float nhA = snh[sA * 16 + l15];
            const float nhB = snh[sB * 16 + l15];
            const unsigned ixA = 1023u - (unsigned)(chunk * 256 + sA * 16 + l15);
            const unsigned ixB = 1023u - (unsigned)(chunk * 256 + sB * 16 + l15);
            const floatx4 nA = {nhA, nhA, nhA, nhA};
            const floatx4 nB = {nhB, nhB, nhB, nhB};
#pragma unroll
            for (int m = 0; m < 2; ++m) {
                floatx4 aA = nA, aB = nB;
                aA = __builtin_amdgcn_mfma_f32_16x16x32_f16(xh[m], ehA, aA, 0, 0, 0);
                aA = __builtin_amdgcn_mfma_f32_16x16x32_f16(xl[m], ehA, aA, 0, 0, 0);
                aA = __builtin_amdgcn_mfma_f32_16x16x32_f16(xh[m], elA, aA, 0, 0, 0);
                aB = __builtin_amdgcn_mfma_f32_16x16x32_f16(xh[m], ehB, aB, 0, 0, 0);
                aB = __builtin_amdgcn_mfma_f32_16x16x32_f16(xl[m], ehB, aB, 0, 0, 0);
                aB = __builtin_amdgcn_mfma_f32_16x16x32_f16(xh[m], elB, aB, 0, 0, 0);
#pragma unroll
                for (int r = 0; r < 4; ++r) {
                    const int q = m * 4 + r;
                    float pA = __uint_as_float((__float_as_uint(aA[r]) & 0xFFFFFC00u) | ixA);
                    float pB = __uint_as_float((__float_as_uint(aB[r]) & 0xFFFFFC00u) | ixB);
                    float t  = __builtin_amdgcn_fmed3f(pA, pB, best[q]);  // 2nd of {pA,pB,best}
                    second[q] = fmaxf(second[q], t);
                    best[q]   = fmaxf(fmaxf(best[q], pA), pB);            // -> v_max3
                }
            }
        }
        __syncthreads();   // all waves done reading before next chunk's staging
    }

    // reduce across the 16 code-lanes (xor over lane bits 0..3)
#pragma unroll
    for (int sh = 1; sh < 16; sh <<= 1) {
#pragma unroll
        for (int q = 0; q < 8; ++q) {
            float bB = __shfl_xor(best[q], sh);
            float sB = __shfl_xor(second[q], sh);
            second[q] = fmaxf(fmaxf(second[q], sB), fminf(best[q], bB));
            best[q]   = fmaxf(best[q], bB);
        }
    }

    if (l15 == 0) {
#pragma unroll
        for (int m = 0; m < 2; ++m) {
#pragma unroll
            for (int r = 0; r < 4; ++r) {
                const int q = m * 4 + r;
                const int token = tok0 + m * 16 + l4 * 4 + r;
                unsigned ub = __float_as_uint(best[q]);
                unsigned us = __float_as_uint(second[q]);
                float bv = __uint_as_float(ub & 0xFFFFFC00u);
                float sv = __uint_as_float(us & 0xFFFFFC00u);
                int eb = (int)((ub >> 23) & 255u);
                int es = (int)((us >> 23) & 255u);
                int em = eb > es ? eb : es;
                em = em > 12 ? em : 12;
                // flag threshold = 4 * packing granule (2^(em-127-12)) + eps
                float thr = __uint_as_float((unsigned)(em - 11) << 23) + DELTA_EPS;
                int k = 1023 - (int)(ub & 1023u);
                out[token] = ((bv - sv) < thr) ? (k | FLAGBIT) : k;
            }
        }
    }
}

// ---------------- rescore: exact fp32 (R1 formula) for flagged tokens ----------------
__global__ __launch_bounds__(256) void vq_rescore(
    const float* __restrict__ w, const float* __restrict__ c,
    const float* __restrict__ cb, const float* __restrict__ nhb,
    int* __restrict__ out)
{
    const int tid  = threadIdx.x;
    const int lane = tid & 63;
    const int wid  = tid >> 6;
    const int t0   = blockIdx.x * 256 + wid * 64;

    int v = out[t0 + lane];
    unsigned long long mask = __ballot((v & FLAGBIT) != 0);
    while (mask) {
        const int src = __ffsll((unsigned long long)mask) - 1;
        mask &= mask - 1;
        const int token = t0 + src;   // wave-uniform

        float x[DIM];
#pragma unroll
        for (int i = 0; i < DIM; ++i) x[i] = w[token * DIM + i] - c[token * DIM + i];
        float x2 = 0.f;
#pragma unroll
        for (int i = 0; i < DIM; ++i) x2 = fmaf(x[i], x[i], x2);

        float dmin = INFINITY;
        int   kbest = 0;
#pragma unroll 2
        for (int i = 0; i < 16; ++i) {
            const int k = lane + 64 * i;           // ascending per lane
            const float* e = cb + k * DIM;
            float dot = 0.f;
#pragma unroll
            for (int j = 0; j < DIM; ++j) dot = fmaf(x[j], e[j], dot);
            float e2 = -2.0f * nhb[k];             // bit-exact |e|^2 (seq-fma in prep)
            float dd = fmaf(-2.0f, dot, x2) + e2;
            if (dd < dmin) { dmin = dd; kbest = k; }
        }
#pragma unroll
        for (int sh = 1; sh < 64; sh <<= 1) {
            float dB = __shfl_xor(dmin, sh);
            int   iB = __shfl_xor(kbest, sh);
            bool take = (dB < dmin) || (dB == dmin && iB < kbest);
            dmin = take ? dB : dmin;
            kbest = take ? iB : kbest;
        }
        if (lane == src) out[token] = kbest;   // clears flag bit
    }
}

extern "C" void kernel_launch(void* const* d_in, const int* in_sizes, int n_in,
                              void* d_out, int out_size, void* d_ws, size_t ws_size,
                              hipStream_t stream) {
    const float* w  = (const float*)d_in[0];   // weights   [4194304]
    const float* c  = (const float*)d_in[1];   // condition [1,32,131072] flat
    const float* cb = (const float*)d_in[2];   // codebook  [1024,32]
    int* out = (int*)d_out;                    // int32 indices [131072]

    char* wsb = (char*)d_ws;
    float*    nhb = (float*)wsb;                       // 4 KB
    _Float16* Eh  = (_Float16*)(wsb + 4096);           // 64 KB (fragment-ordered)
    _Float16* El  = (_Float16*)(wsb + 4096 + 65536);   // 64 KB (fragment-ordered)

    vq_prep<<<NCODE / 64, 64, 0, stream>>>(cb, nhb, Eh, El);
    vq_main<<<NTOK / 128, 256, 0, stream>>>(w, c, nhb, Eh, El, out);
    vq_rescore<<<NTOK / 256, 256, 0, stream>>>(w, c, cb, nhb, out);
}

// Round 6
// 57.574 us; speedup vs baseline: 6.0041x; 1.2744x over previous
//
#include <hip/hip_runtime.h>

#define TOTAL     4194304
#define DIM       32
#define NTOK      (TOTAL / DIM)   // 131072 tokens
#define NCODE     1024
#define NCHUNK    8
#define CCODES    128             // codes per chunk
#define DELTA_EPS 2e-3f
#define FLAGBIT   0x40000000

typedef _Float16 half8   __attribute__((ext_vector_type(8)));
typedef float    floatx4 __attribute__((ext_vector_type(4)));

#define GLOAD_LDS16(g, l) \
    __builtin_amdgcn_global_load_lds((const __attribute__((address_space(1))) void*)(g), \
                                     (__attribute__((address_space(3))) void*)(l), 16, 0, 0)
#define GLOAD_LDS4(g, l) \
    __builtin_amdgcn_global_load_lds((const __attribute__((address_space(1))) void*)(g), \
                                     (__attribute__((address_space(3))) void*)(l), 4, 0, 0)

// ---------------- prep: codebook -> f16 hi/lo split in FRAGMENT ORDER + (-0.5*|e|^2) ----
// Fragment slot for code k: chunk = k>>7 (128-code chunks), step = (k&127)>>4, l15 = k&15.
// slot = chunk*512 + step*64 + l4*16 + l15  (8 halves = 16 B per slot).
// Main reads/stages with purely linear (lane*16B) addressing -> zero bank conflicts.
__global__ __launch_bounds__(64) void vq_prep(
    const float* __restrict__ cb, float* __restrict__ nhb,
    _Float16* __restrict__ Eh, _Float16* __restrict__ El)
{
    const int k = blockIdx.x * 64 + threadIdx.x;   // code id
    const float4* e4 = reinterpret_cast<const float4*>(cb) + (size_t)k * 8;
    float v[DIM];
    float4 t[8];
#pragma unroll
    for (int j = 0; j < 8; ++j) t[j] = e4[j];
#pragma unroll
    for (int j = 0; j < 8; ++j) {
        v[4 * j + 0] = t[j].x; v[4 * j + 1] = t[j].y;
        v[4 * j + 2] = t[j].z; v[4 * j + 3] = t[j].w;
    }
    float e2 = 0.0f;
#pragma unroll
    for (int i = 0; i < DIM; ++i) e2 = fmaf(v[i], v[i], e2);   // sequential: matches rescore
    nhb[k] = -0.5f * e2;

    const int chunk = k >> 7, within = k & 127;
    const int step = within >> 4, l15 = within & 15;
#pragma unroll
    for (int l4 = 0; l4 < 4; ++l4) {
        half8 h, lo;
#pragma unroll
        for (int j = 0; j < 8; ++j) {
            float x = v[l4 * 8 + j];
            _Float16 hh = (_Float16)x;
            h[j]  = hh;
            lo[j] = (_Float16)(x - (float)hh);
        }
        const int slot = chunk * 512 + step * 64 + l4 * 16 + l15;
        *reinterpret_cast<half8*>(Eh + (size_t)slot * 8) = h;
        *reinterpret_cast<half8*>(El + (size_t)slot * 8) = lo;
    }
}

// ---------------- main: MFMA argmax + inline exact rescore of near-ties ----------------
__global__ __launch_bounds__(256) void vq_main(
    const float* __restrict__ w, const float* __restrict__ c,
    const float* __restrict__ nhb, const _Float16* __restrict__ Eh,
    const _Float16* __restrict__ El, const float* __restrict__ cb,
    int* __restrict__ out)
{
    __shared__ _Float16 sEh[2][512 * 8];   // 2 x 8 KB
    __shared__ _Float16 sEl[2][512 * 8];   // 2 x 8 KB
    __shared__ float    snh[2][CCODES];    // 2 x 512 B
    __shared__ int      sOut[128];         // 512 B result scratch

    const int tid  = threadIdx.x;
    const int lane = tid & 63;
    const int wid  = tid >> 6;
    const int tok0 = blockIdx.x * 128 + wid * 32;   // 32 tokens per wave
    const int l15  = lane & 15;
    const int l4   = lane >> 4;

    // A fragments: 2 tiles of 16 tokens. A[row=l15][k=l4*8+j]
    half8 xh[2], xl[2];
#pragma unroll
    for (int m = 0; m < 2; ++m) {
        const int token = tok0 + m * 16 + l15;
        const float4* pw = reinterpret_cast<const float4*>(w + (size_t)token * DIM + l4 * 8);
        const float4* pc = reinterpret_cast<const float4*>(c + (size_t)token * DIM + l4 * 8);
        float4 a0 = pw[0], a1 = pw[1], b0 = pc[0], b1 = pc[1];
        float xs[8] = {a0.x - b0.x, a0.y - b0.y, a0.z - b0.z, a0.w - b0.w,
                       a1.x - b1.x, a1.y - b1.y, a1.z - b1.z, a1.w - b1.w};
#pragma unroll
        for (int j = 0; j < 8; ++j) {
            _Float16 h = (_Float16)xs[j];
            xh[m][j] = h;
            xl[m][j] = (_Float16)(xs[j] - (float)h);
        }
    }

    const float NEGINF = __uint_as_float(0xFF800000u);
    float best[8], second[8];
#pragma unroll
    for (int q = 0; q < 8; ++q) { best[q] = NEGINF; second[q] = NEGINF; }

    // ---- stage chunk `ch` into buffer `b` (all-linear addressing, async to LDS)
    auto stage = [&](int ch, int b) {
        const _Float16* gh = Eh + (size_t)ch * 4096;
        const _Float16* gl = El + (size_t)ch * 4096;
#pragma unroll
        for (int r2 = 0; r2 < 2; ++r2) {
            const int slot = r2 * 256 + wid * 64;   // wave-uniform LDS base slot
            GLOAD_LDS16(gh + (size_t)(slot + lane) * 8, &sEh[b][(size_t)slot * 8]);
            GLOAD_LDS16(gl + (size_t)(slot + lane) * 8, &sEl[b][(size_t)slot * 8]);
        }
        if (wid < 2) GLOAD_LDS4(nhb + ch * CCODES + wid * 64 + lane, &snh[b][wid * 64]);
    };

    stage(0, 0);
    __syncthreads();   // startup drain (once)

    for (int ch = 0; ch < NCHUNK; ++ch) {
        const int b = ch & 1;
        if (ch < NCHUNK - 1) stage(ch + 1, b ^ 1);   // prefetch: lands under compute

        // 8 steps of 16 codes, processed in pairs (for med3 second-tracking)
#pragma unroll
        for (int sp = 0; sp < 4; ++sp) {
            const int sA = 2 * sp, sB = 2 * sp + 1;
            const half8 ehA = *reinterpret_cast<const half8*>(&sEh[b][(sA * 64 + lane) * 8]);
            const half8 elA = *reinterpret_cast<const half8*>(&sEl[b][(sA * 64 + lane) * 8]);
            const half8 ehB = *reinterpret_cast<const half8*>(&sEh[b][(sB * 64 + lane) * 8]);
            const half8 elB = *reinterpret_cast<const half8*>(&sEl[b][(sB * 64 + lane) * 8]);
            const float nhA = snh[b][sA * 16 + l15];
            const float nhB = snh[b][sB * 16 + l15];
            const unsigned ixA = 1023u - (unsigned)(ch * CCODES + sA * 16 + l15);
            const unsigned ixB = 1023u - (unsigned)(ch * CCODES + sB * 16 + l15);
            const floatx4 nA = {nhA, nhA, nhA, nhA};
            const floatx4 nB = {nhB, nhB, nhB, nhB};
#pragma unroll
            for (int m = 0; m < 2; ++m) {
                floatx4 aA = __builtin_amdgcn_mfma_f32_16x16x32_f16(xh[m], ehA, nA, 0, 0, 0);
                aA = __builtin_amdgcn_mfma_f32_16x16x32_f16(xl[m], ehA, aA, 0, 0, 0);
                aA = __builtin_amdgcn_mfma_f32_16x16x32_f16(xh[m], elA, aA, 0, 0, 0);
                floatx4 aB = __builtin_amdgcn_mfma_f32_16x16x32_f16(xh[m], ehB, nB, 0, 0, 0);
                aB = __builtin_amdgcn_mfma_f32_16x16x32_f16(xl[m], ehB, aB, 0, 0, 0);
                aB = __builtin_amdgcn_mfma_f32_16x16x32_f16(xh[m], elB, aB, 0, 0, 0);
#pragma unroll
                for (int r = 0; r < 4; ++r) {
                    const int q = m * 4 + r;
                    float pA = __uint_as_float((__float_as_uint(aA[r]) & 0xFFFFFC00u) | ixA);
                    float pB = __uint_as_float((__float_as_uint(aB[r]) & 0xFFFFFC00u) | ixB);
                    float t  = __builtin_amdgcn_fmed3f(pA, pB, best[q]);  // 2nd of {pA,pB,best}
                    second[q] = fmaxf(second[q], t);
                    best[q]   = fmaxf(fmaxf(best[q], pA), pB);            // -> v_max3
                }
            }
        }
        __syncthreads();   // drains prefetch vmcnt (issued a full phase ago) + buffer handoff
    }

    // reduce across the 16 code-lanes (xor over lane bits 0..3)
#pragma unroll
    for (int sh = 1; sh < 16; sh <<= 1) {
#pragma unroll
        for (int q = 0; q < 8; ++q) {
            float bB = __shfl_xor(best[q], sh);
            float sB = __shfl_xor(second[q], sh);
            second[q] = fmaxf(fmaxf(second[q], sB), fminf(best[q], bB));
            best[q]   = fmaxf(best[q], bB);
        }
    }

    // stage per-token results (k | optional FLAGBIT) into wave-local LDS scratch
    if (l15 == 0) {
#pragma unroll
        for (int m = 0; m < 2; ++m) {
#pragma unroll
            for (int r = 0; r < 4; ++r) {
                const int q = m * 4 + r;
                unsigned ub = __float_as_uint(best[q]);
                unsigned us = __float_as_uint(second[q]);
                float bv = __uint_as_float(ub & 0xFFFFFC00u);
                float sv = __uint_as_float(us & 0xFFFFFC00u);
                int eb = (int)((ub >> 23) & 255u);
                int es = (int)((us >> 23) & 255u);
                int em = eb > es ? eb : es;
                em = em > 12 ? em : 12;
                // flag threshold = 4 * packing granule (2^(em-127-12)) + eps
                float thr = __uint_as_float((unsigned)(em - 11) << 23) + DELTA_EPS;
                int k = 1023 - (int)(ub & 1023u);
                sOut[wid * 32 + m * 16 + l4 * 4 + r] = ((bv - sv) < thr) ? (k | FLAGBIT) : k;
            }
        }
    }

    // lane i (<32) owns token tok0+i; rescore flagged tokens exactly (wave-cooperative)
    int myval = 0;
    if (lane < 32) myval = sOut[wid * 32 + lane];
    unsigned long long mask = __ballot(lane < 32 && (myval & FLAGBIT));
    while (mask) {
        const int src = __ffsll(mask) - 1;
        mask &= mask - 1;
        const int token = tok0 + src;   // wave-uniform

        float x[DIM];
#pragma unroll
        for (int i = 0; i < DIM; ++i) x[i] = w[(size_t)token * DIM + i] - c[(size_t)token * DIM + i];
        float x2 = 0.f;
#pragma unroll
        for (int i = 0; i < DIM; ++i) x2 = fmaf(x[i], x[i], x2);

        float dmin = INFINITY;
        int   kbest = 0;
#pragma unroll 2
        for (int i = 0; i < 16; ++i) {
            const int k = lane + 64 * i;           // ascending per lane
            const float* e = cb + (size_t)k * DIM;
            float dot = 0.f;
#pragma unroll
            for (int j = 0; j < DIM; ++j) dot = fmaf(x[j], e[j], dot);
            float e2 = -2.0f * nhb[k];             // bit-exact |e|^2 (seq-fma in prep)
            float dd = fmaf(-2.0f, dot, x2) + e2;
            if (dd < dmin) { dmin = dd; kbest = k; }
        }
#pragma unroll
        for (int sh = 1; sh < 64; sh <<= 1) {
            float dB = __shfl_xor(dmin, sh);
            int   iB = __shfl_xor(kbest, sh);
            bool take = (dB < dmin) || (dB == dmin && iB < kbest);
            dmin = take ? dB : dmin;
            kbest = take ? iB : kbest;
        }
        if (lane == src) myval = kbest;   // exact index, flag cleared
    }
    if (lane < 32) out[tok0 + lane] = myval;   // coalesced 128 B per wave
}

extern "C" void kernel_launch(void* const* d_in, const int* in_sizes, int n_in,
                              void* d_out, int out_size, void* d_ws, size_t ws_size,
                              hipStream_t stream) {
    const float* w  = (const float*)d_in[0];   // weights   [4194304]
    const float* c  = (const float*)d_in[1];   // condition [1,32,131072] flat
    const float* cb = (const float*)d_in[2];   // codebook  [1024,32]
    int* out = (int*)d_out;                    // int32 indices [131072]

    char* wsb = (char*)d_ws;
    float*    nhb = (float*)wsb;                       // 4 KB
    _Float16* Eh  = (_Float16*)(wsb + 4096);           // 64 KB (fragment-ordered)
    _Float16* El  = (_Float16*)(wsb + 4096 + 65536);   // 64 KB (fragment-ordered)

    vq_prep<<<NCODE / 64, 64, 0, stream>>>(cb, nhb, Eh, El);
    vq_main<<<NTOK / 128, 256, 0, stream>>>(w, c, nhb, Eh, El, cb, out);
}